// Round 15
// baseline (599.352 us; speedup 1.0000x reference)
//
#include <hip/hip_runtime.h>
#include <hip/hip_bf16.h>

typedef _Float16 f16;
typedef __attribute__((ext_vector_type(8))) _Float16 f16x8;
typedef __attribute__((ext_vector_type(4))) _Float16 f16x4;
typedef __attribute__((ext_vector_type(4))) float f32x4;

#define DIM 1024
#define HEADS 16
#define DHEAD 64
#define MLPD 4096
#define NQ 16384
#define NW 1024
#define MCHUNK 32

// ---------------- async global->LDS (16B per lane) ----------------
__device__ __forceinline__ void glds16(const f16* g, f16* l) {
  __builtin_amdgcn_global_load_lds(
      (const __attribute__((address_space(1))) void*)g,
      (__attribute__((address_space(3))) void*)l, 16, 0, 0);
}

// fast 1/x and 1/sqrt(x) (v_rcp/v_rsq, ~1ulp; error budget 0.29 >> this)
__device__ __forceinline__ float fast_rcp(float x) {
  float r;
  asm("v_rcp_f32 %0, %1" : "=v"(r) : "v"(x));
  return r;
}
__device__ __forceinline__ float fast_rsq(float x) {
  float r;
  asm("v_rsq_f32 %0, %1" : "=v"(r) : "v"(x));
  return r;
}

// ---------------- LayerNorm(1024): f32 in -> f16 out ----------------
__device__ __forceinline__ void ln_body(const float* __restrict__ X,
                                        const float* __restrict__ w,
                                        const float* __restrict__ b,
                                        f16* __restrict__ O, int t) {
  const float4 v = ((const float4*)X)[t];
  float s = v.x + v.y + v.z + v.w;
  float s2 = v.x * v.x + v.y * v.y + v.z * v.z + v.w * v.w;
#pragma unroll
  for (int m = 1; m < 64; m <<= 1) {
    s += __shfl_xor(s, m);
    s2 += __shfl_xor(s2, m);
  }
  __shared__ float ps[4], ps2[4];
  const int lane = t & 63, wid = t >> 6;
  if (lane == 0) { ps[wid] = s; ps2[wid] = s2; }
  __syncthreads();
  s = ps[0] + ps[1] + ps[2] + ps[3];
  s2 = ps2[0] + ps2[1] + ps2[2] + ps2[3];
  const float mu = s * (1.0f / DIM);
  const float inv = rsqrtf(s2 * (1.0f / DIM) - mu * mu + 1e-5f);
  const float4 wv = ((const float4*)w)[t];
  const float4 bv = ((const float4*)b)[t];
  f16x4 o;
  o[0] = (f16)((v.x - mu) * inv * wv.x + bv.x);
  o[1] = (f16)((v.y - mu) * inv * wv.y + bv.y);
  o[2] = (f16)((v.z - mu) * inv * wv.z + bv.z);
  o[3] = (f16)((v.w - mu) * inv * wv.w + bv.w);
  *(f16x4*)(O + t * 4) = o;
}

__global__ __launch_bounds__(256) void ln_f16_k(
    const float* __restrict__ X, const float* __restrict__ w,
    const float* __restrict__ b, f16* __restrict__ O) {
  const long row = blockIdx.x;
  ln_body(X + row * DIM, w, b, O + row * DIM, threadIdx.x);
}

// merged LN1 for queries + prototypes (one launch)
__global__ __launch_bounds__(256) void ln1_all_k(
    const float* __restrict__ q, const float* __restrict__ p,
    const float* __restrict__ w, const float* __restrict__ b,
    f16* __restrict__ QN, f16* __restrict__ PN) {
  const long row = blockIdx.x;
  if (row < NQ)
    ln_body(q + row * DIM, w, b, QN + row * DIM, threadIdx.x);
  else
    ln_body(p + (row - NQ) * DIM, w, b, PN + (row - NQ) * DIM, threadIdx.x);
}

// ---------------- merged transpose+cast: all 5 weights in one launch ------------
__global__ __launch_bounds__(256) void tcast_all_k(
    const float* __restrict__ wq, const float* __restrict__ wk,
    const float* __restrict__ wv, const float* __restrict__ w1,
    const float* __restrict__ w2, f16* WQT, f16* WKT, f16* WVT, f16* W1T,
    f16* W2T) {
  const int id = blockIdx.x;
  const float* X;
  f16* O;
  int R, C, tx, ty;
  if (id < 3072) {
    const int which = id >> 10, l = id & 1023;
    X = which == 0 ? wq : which == 1 ? wk : wv;
    O = which == 0 ? WQT : which == 1 ? WKT : WVT;
    R = 1024; C = 1024; tx = l & 31; ty = l >> 5;
  } else if (id < 7168) {
    const int l = id - 3072;
    X = w1; O = W1T; R = 1024; C = 4096; tx = l & 127; ty = l >> 7;
  } else {
    const int l = id - 7168;
    X = w2; O = W2T; R = 4096; C = 1024; tx = l & 31; ty = l >> 5;
  }
  __shared__ float tile[32][33];
  const int c0 = tx * 32, r0 = ty * 32;
  const int x = threadIdx.x, y = threadIdx.y;
#pragma unroll
  for (int j = 0; j < 4; ++j)
    tile[y + j * 8][x] = X[(long)(r0 + y + j * 8) * C + c0 + x];
  __syncthreads();
#pragma unroll
  for (int j = 0; j < 4; ++j)
    O[(long)(c0 + y + j * 8) * R + r0 + x] = (f16)tile[x][y + j * 8];
}

// ---------------- M_h partials from combined KV[1024][2048] ----------------
__global__ __launch_bounds__(256) void calc_m_part_k(const f16* __restrict__ KV,
                                                     float* __restrict__ Mp) {
  const int h = blockIdx.x, ch = blockIdx.y;
  const int t = threadIdx.x;
  const int d1 = t >> 2;
  const int d2b = (t & 3) * 16;
  float acc[16] = {};
  const int n0 = ch * (NW / MCHUNK);
#pragma unroll 4
  for (int n = n0; n < n0 + NW / MCHUNK; ++n) {
    const float kv = (float)KV[(long)n * 2048 + h * DHEAD + d1];
    const f16x8* vp = (const f16x8*)&KV[(long)n * 2048 + 1024 + h * DHEAD + d2b];
    const f16x8 v0 = vp[0], v1 = vp[1];
#pragma unroll
    for (int j = 0; j < 8; ++j) acc[j] += kv * (float)v0[j];
#pragma unroll
    for (int j = 0; j < 8; ++j) acc[8 + j] += kv * (float)v1[j];
  }
  float* o = &Mp[((long)(h * MCHUNK + ch)) * 4096 + d1 * 64 + d2b];
#pragma unroll
  for (int j = 0; j < 16; ++j) o[j] = acc[j];
}

__global__ __launch_bounds__(256) void calc_m_reduce_k(const float* __restrict__ Mp,
                                                       float* __restrict__ Mo) {
  const int h = blockIdx.x;
  const int t = threadIdx.x;
#pragma unroll
  for (int e = t; e < 4096; e += 256) {
    float s = 0.f;
#pragma unroll
    for (int c = 0; c < MCHUNK; ++c)
      s += Mp[((long)(h * MCHUNK + c)) * 4096 + e];
    Mo[h * 4096 + e] = s;
  }
}

// ---------------- W_eff^T[j][i] = sum_d M[h(i)][i%64][d] * wo[h*64+d][j] ----------------
__global__ __launch_bounds__(256) void calc_wefft_k(const float* __restrict__ M,
                                                    const float* __restrict__ wo,
                                                    f16* __restrict__ Wt) {
  const int h = blockIdx.x, jt = blockIdx.y;
  const int t = threadIdx.x;
  const int jl = t & 63;
  const int il0 = (t >> 6) * 16;
  const int j = jt * 64 + jl;
  float acc[16] = {};
  for (int d = 0; d < DHEAD; ++d) {
    const float w = wo[(long)(h * DHEAD + d) * DIM + j];
    const float* mrow = &M[h * 4096 + il0 * 64 + d];
#pragma unroll
    for (int r = 0; r < 16; ++r) acc[r] += mrow[r * 64] * w;
  }
#pragma unroll
  for (int r = 0; r < 16; ++r)
    Wt[(long)j * DIM + h * DHEAD + il0 + r] = (f16)acc[r];
}

// ============ 256x128 one-barrier-per-tile GEMM, 2 blocks/CU ====================
// R14 analysis: 512-thr block w/ 128-AGPR acc caps at 2 waves/SIMD -> can NEVER
// be 2/CU (reg file 512/lane/SIMD). This round keeps the identical per-wave
// geometry (128x64 out, acc[8][4], same swizzle, one-barrier body) but shrinks
// the block: 256 thr = 4 waves (2Mx2N), tile 256x128, BK=32, LDS 48KB x 2bufs.
// => 2 co-resident blocks/CU (8 waves, 1952 regs/SIMD <= 2048, 96KB LDS <= 160)
// to overlap the ~3000cy/tile of exposed staging-latency + barrier drain.
// launch_bounds(256,2): reg cap 256/wave (same as proven R12 config; NOT >2 —
// R9/R10/R13 lesson: higher min-waves spills the accumulator -> GBs of scratch).
enum {
  EPI_F16 = 0,       // f16 out
  EPI_L2N = 1,       // per-head l2norm, f16 out
  EPI_BIAS_RES = 2,  // f32 out = acc + bias + f32 resid (out may alias resid)
  EPI_GELU = 3,      // f16 out = gelu(acc + bias), sigmoid form
  EPI_KV = 4         // N=2048 combined K|V: c0<1024 -> l2norm (K half), else cast
};

template <int EPI>
__global__ __launch_bounds__(256, 2) void gemm256(
    const f16* __restrict__ A, const f16* __restrict__ Bt, int M, int N, int K,
    const float* __restrict__ bias, const float* resid, void* out) {
  // per buf: A[256][32] at 0 (8192 f16), B[128][32] at 8192 (4096 f16);
  // buf stride 12288 f16; total 24576 f16 = 48KB
  __shared__ __align__(16) f16 lds[24576];

  const int tid = threadIdx.x;
  const int lane = tid & 63;
  const int wid = tid >> 6;   // 0..3
  const int wm = wid >> 1;    // 0..1
  const int wn = wid & 1;     // 0..1
  const int l15 = lane & 15;

  // M-slab XCD mapping (block orig -> XCD orig%8)
  int bm, bn;
  {
    const int orig = blockIdx.y * gridDim.x + blockIdx.x;
    if ((gridDim.x & 7) == 0) {
      const int slab = orig & 7;
      const int idx = orig >> 3;
      const int sm = gridDim.x >> 3;
      bm = slab * sm + idx % sm;
      bn = idx / sm;
    } else {
      bm = blockIdx.x;
      bn = blockIdx.y;
    }
  }

  // staging: thread t -> row (t>>2) within a 64-row sub-stage, slot t&3;
  // source col pre-XORed with ((t>>3)&3) = ((row>>1)&3) (both-sides involution)
  const int scol8 = (((tid & 3) ^ ((tid >> 3) & 3))) * 8;
  const f16* aSrc = A + (long)(bm * 256 + (tid >> 2)) * K + scol8;
  const f16* bSrc = Bt + (long)(bn * 128 + (tid >> 2)) * K + scol8;
  const long r64 = (long)64 * K;
  const int tid8 = tid * 8;

  const int rslot8 = (((lane >> 4) ^ ((l15 >> 1) & 3))) * 8;
  const int aRdBase = (wm * 128 + l15) * 32 + rslot8;
  const int bRdBase = 8192 + (wn * 64 + l15) * 32 + rslot8;

  f32x4 acc[8][4] = {};
  const int NT = K >> 5;  // BK=32 tiles

#define STAGE(Ld, t)                                     \
  {                                                      \
    const long ko = (long)(t) * 32;                      \
    glds16(aSrc + ko, (Ld) + tid8);                      \
    glds16(aSrc + r64 + ko, (Ld) + 2048 + tid8);         \
    glds16(aSrc + 2 * r64 + ko, (Ld) + 4096 + tid8);     \
    glds16(aSrc + 3 * r64 + ko, (Ld) + 6144 + tid8);     \
    glds16(bSrc + ko, (Ld) + 8192 + tid8);               \
    glds16(bSrc + r64 + ko, (Ld) + 10240 + tid8);        \
  }

#define BURST(AF, BF, MB)                                                 \
  __builtin_amdgcn_s_setprio(1);                                          \
  _Pragma("unroll") for (int j = 0; j < 4; ++j)                           \
      _Pragma("unroll") for (int nj = 0; nj < 4; ++nj)                    \
          acc[(MB) + j][nj] = __builtin_amdgcn_mfma_f32_16x16x32_f16(     \
              AF[j], BF[nj], acc[(MB) + j][nj], 0, 0, 0);                 \
  __builtin_amdgcn_s_setprio(0)

  // prologue: stage tile 0, sync (drains vmcnt)
  STAGE(lds, 0);
  __syncthreads();

  for (int g = 0; g < NT; ++g) {
    f16* L = &lds[(g & 1) * 12288];
    f16* Lo = &lds[((g & 1) ^ 1) * 12288];
    const bool s1 = (g + 1) < NT;

    if (s1) STAGE(Lo, g + 1);
    f16x8 aA[4], aB[4], bA[4];
#pragma unroll
    for (int j = 0; j < 4; ++j) bA[j] = *(const f16x8*)&L[bRdBase + j * 512];
#pragma unroll
    for (int j = 0; j < 4; ++j) aA[j] = *(const f16x8*)&L[aRdBase + j * 512];
#pragma unroll
    for (int j = 0; j < 4; ++j)
      aB[j] = *(const f16x8*)&L[aRdBase + 2048 + j * 512];
    BURST(aA, bA, 0);
    BURST(aB, bA, 4);

    __syncthreads();  // drains vm+lgkm: tile g+1 landed, buf L free
  }
#undef STAGE
#undef BURST

  // epilogue
  const int r0 = bm * 256 + wm * 128;
  const int c0 = bn * 128 + wn * 64;  // == one head for L2N / K-half of EPI_KV
  const int lr = (lane >> 4) * 4;
  const int lc = l15;

#pragma unroll
  for (int mi = 0; mi < 8; ++mi) {
#pragma unroll
    for (int i = 0; i < 4; ++i) {
      const long r = r0 + mi * 16 + lr + i;
      if (EPI == EPI_L2N || EPI == EPI_KV) {
        if (EPI == EPI_L2N || c0 < 1024) {
          float ss = 0.f;
#pragma unroll
          for (int nj = 0; nj < 4; ++nj) {
            const float x = acc[mi][nj][i];
            ss += x * x;
          }
          ss += __shfl_xor(ss, 1);
          ss += __shfl_xor(ss, 2);
          ss += __shfl_xor(ss, 4);
          ss += __shfl_xor(ss, 8);
          const float inv = fast_rsq(fmaxf(ss, 1e-24f));
#pragma unroll
          for (int nj = 0; nj < 4; ++nj)
            ((f16*)out)[r * N + c0 + nj * 16 + lc] = (f16)(acc[mi][nj][i] * inv);
        } else {  // V half: plain cast
#pragma unroll
          for (int nj = 0; nj < 4; ++nj)
            ((f16*)out)[r * N + c0 + nj * 16 + lc] = (f16)acc[mi][nj][i];
        }
      } else if (EPI == EPI_F16) {
#pragma unroll
        for (int nj = 0; nj < 4; ++nj)
          ((f16*)out)[r * N + c0 + nj * 16 + lc] = (f16)acc[mi][nj][i];
      } else if (EPI == EPI_BIAS_RES) {
#pragma unroll
        for (int nj = 0; nj < 4; ++nj) {
          const long c2 = c0 + nj * 16 + lc;
          ((float*)out)[r * N + c2] = acc[mi][nj][i] + bias[c2] + resid[r * N + c2];
        }
      } else {  // EPI_GELU: x*sigmoid(1.5957691*(x+0.044715x^3)), exp+rcp only
#pragma unroll
        for (int nj = 0; nj < 4; ++nj) {
          const long c2 = c0 + nj * 16 + lc;
          const float x = acc[mi][nj][i] + bias[c2];
          const float x2 = x * x;
          const float t = __builtin_fmaf(0.044715f * x2, x, x);
          const float y = fminf(-1.5957691216057308f * t, 88.0f);
          const float z = __expf(y);
          ((f16*)out)[r * N + c2] = (f16)(x * fast_rcp(1.0f + z));
        }
      }
    }
  }
}

extern "C" void kernel_launch(void* const* d_in, const int* in_sizes, int n_in,
                              void* d_out, int out_size, void* d_ws, size_t ws_size,
                              hipStream_t stream) {
  (void)in_sizes; (void)n_in; (void)out_size;
  const float* queries = (const float*)d_in[0];
  const float* prototypes = (const float*)d_in[1];
  const float* ln1_w = (const float*)d_in[2];
  const float* ln1_b = (const float*)d_in[3];
  const float* wq = (const float*)d_in[4];
  const float* wk = (const float*)d_in[5];
  const float* wv = (const float*)d_in[6];
  const float* wo = (const float*)d_in[7];
  const float* bo = (const float*)d_in[8];
  const float* ln2_w = (const float*)d_in[9];
  const float* ln2_b = (const float*)d_in[10];
  const float* w1 = (const float*)d_in[11];
  const float* b1 = (const float*)d_in[12];
  const float* w2 = (const float*)d_in[13];
  const float* b2 = (const float*)d_in[14];

  char* ws = (char*)d_ws;
  const size_t MB = 1024ull * 1024ull;
  if (ws_size < 176ull * MB) return;  // layout needs 176MB

  // transient region (dead before MLP; G aliases it)
  f16* QN = (f16*)(ws + 0);             // 32MB [16384][1024]
  f16* QHAT = (f16*)(ws + 32 * MB);     // 32MB
  f16* PN = (f16*)(ws + 64 * MB);       // 2MB
  f16* WQT = (f16*)(ws + 66 * MB);      // 2MB
  f16* WKT = (f16*)(ws + 68 * MB);      // 2MB  (WKT|WVT contiguous = KV weights)
  f16* WVT = (f16*)(ws + 70 * MB);      // 2MB
  f16* KV = (f16*)(ws + 72 * MB);       // 4MB [1024][2048]: khat | v
  float* Mbuf = (float*)(ws + 76 * MB); // 256KB
  f16* WEFFT = (f16*)(ws + 77 * MB);    // 2MB
  float* Mpart = (float*)(ws + 0);      // 8MB, aliases QN (dead by then)
  // persistent region
  f16* G = (f16*)(ws + 0);              // 128MB [16384][4096], aliases transients
  f16* HBF = (f16*)(ws + 128 * MB);     // 32MB
  f16* W1T = (f16*)(ws + 160 * MB);     // 8MB [4096][1024]
  f16* W2T = (f16*)(ws + 168 * MB);     // 8MB [1024][4096]
  float* RES2 = (float*)d_out;          // residual2 lives in d_out (f32, 64MB)

  // LN1 (queries + prototypes, one launch)
  ln1_all_k<<<NQ + NW, 256, 0, stream>>>(queries, prototypes, ln1_w, ln1_b, QN, PN);
  // all 5 weight transpose-casts, one launch
  tcast_all_k<<<11264, dim3(32, 8), 0, stream>>>(wq, wk, wv, w1, w2, WQT, WKT,
                                                 WVT, W1T, W2T);

  // q projection (+fused per-head l2norm)
  gemm256<EPI_L2N><<<dim3(NQ / 256, DIM / 128), 256, 0, stream>>>(
      QN, WQT, NQ, DIM, DIM, nullptr, nullptr, QHAT);
  // merged k+v projection: N=2048 against WKT|WVT, l2norm on K half
  gemm256<EPI_KV><<<dim3(NW / 256, 2048 / 128), 256, 0, stream>>>(
      PN, WKT, NW, 2048, DIM, nullptr, nullptr, KV);

  // attention collapse
  calc_m_part_k<<<dim3(HEADS, MCHUNK), 256, 0, stream>>>(KV, Mpart);
  calc_m_reduce_k<<<HEADS, 256, 0, stream>>>(Mpart, Mbuf);
  calc_wefft_k<<<dim3(HEADS, 16), 256, 0, stream>>>(Mbuf, wo, WEFFT);

  // attn-out + wo + bias + residual -> RES2 (f32, in d_out)
  gemm256<EPI_BIAS_RES><<<dim3(NQ / 256, DIM / 128), 256, 0, stream>>>(
      QHAT, WEFFT, NQ, DIM, DIM, bo, queries, RES2);

  // LN2 (reads d_out f32)
  ln_f16_k<<<NQ, 256, 0, stream>>>(RES2, ln2_w, ln2_b, HBF);

  // MLP, unchunked, full grids
  gemm256<EPI_GELU><<<dim3(NQ / 256, MLPD / 128), 256, 0, stream>>>(
      HBF, W1T, NQ, MLPD, DIM, b1, nullptr, G);
  gemm256<EPI_BIAS_RES><<<dim3(NQ / 256, DIM / 128), 256, 0, stream>>>(
      G, W2T, NQ, DIM, MLPD, b2, RES2, (float*)d_out);
}

// Round 16
// 582.205 us; speedup vs baseline: 1.0295x; 1.0295x over previous
//
#include <hip/hip_runtime.h>
#include <hip/hip_bf16.h>

typedef _Float16 f16;
typedef __attribute__((ext_vector_type(8))) _Float16 f16x8;
typedef __attribute__((ext_vector_type(4))) _Float16 f16x4;
typedef __attribute__((ext_vector_type(4))) float f32x4;

#define DIM 1024
#define HEADS 16
#define DHEAD 64
#define MLPD 4096
#define NQ 16384
#define NW 1024
#define MCHUNK 32

// ---------------- async global->LDS (16B per lane) ----------------
__device__ __forceinline__ void glds16(const f16* g, f16* l) {
  __builtin_amdgcn_global_load_lds(
      (const __attribute__((address_space(1))) void*)g,
      (__attribute__((address_space(3))) void*)l, 16, 0, 0);
}

// fast 1/x and 1/sqrt(x) (v_rcp/v_rsq, ~1ulp; error budget 0.29 >> this)
__device__ __forceinline__ float fast_rcp(float x) {
  float r;
  asm("v_rcp_f32 %0, %1" : "=v"(r) : "v"(x));
  return r;
}
__device__ __forceinline__ float fast_rsq(float x) {
  float r;
  asm("v_rsq_f32 %0, %1" : "=v"(r) : "v"(x));
  return r;
}

// ---------------- LayerNorm(1024): f32 in -> f16 out ----------------
__device__ __forceinline__ void ln_body(const float* __restrict__ X,
                                        const float* __restrict__ w,
                                        const float* __restrict__ b,
                                        f16* __restrict__ O, int t) {
  const float4 v = ((const float4*)X)[t];
  float s = v.x + v.y + v.z + v.w;
  float s2 = v.x * v.x + v.y * v.y + v.z * v.z + v.w * v.w;
#pragma unroll
  for (int m = 1; m < 64; m <<= 1) {
    s += __shfl_xor(s, m);
    s2 += __shfl_xor(s2, m);
  }
  __shared__ float ps[4], ps2[4];
  const int lane = t & 63, wid = t >> 6;
  if (lane == 0) { ps[wid] = s; ps2[wid] = s2; }
  __syncthreads();
  s = ps[0] + ps[1] + ps[2] + ps[3];
  s2 = ps2[0] + ps2[1] + ps2[2] + ps2[3];
  const float mu = s * (1.0f / DIM);
  const float inv = rsqrtf(s2 * (1.0f / DIM) - mu * mu + 1e-5f);
  const float4 wv = ((const float4*)w)[t];
  const float4 bv = ((const float4*)b)[t];
  f16x4 o;
  o[0] = (f16)((v.x - mu) * inv * wv.x + bv.x);
  o[1] = (f16)((v.y - mu) * inv * wv.y + bv.y);
  o[2] = (f16)((v.z - mu) * inv * wv.z + bv.z);
  o[3] = (f16)((v.w - mu) * inv * wv.w + bv.w);
  *(f16x4*)(O + t * 4) = o;
}

__global__ __launch_bounds__(256) void ln_f16_k(
    const float* __restrict__ X, const float* __restrict__ w,
    const float* __restrict__ b, f16* __restrict__ O) {
  const long row = blockIdx.x;
  ln_body(X + row * DIM, w, b, O + row * DIM, threadIdx.x);
}

// merged LN1 for queries + prototypes (one launch)
__global__ __launch_bounds__(256) void ln1_all_k(
    const float* __restrict__ q, const float* __restrict__ p,
    const float* __restrict__ w, const float* __restrict__ b,
    f16* __restrict__ QN, f16* __restrict__ PN) {
  const long row = blockIdx.x;
  if (row < NQ)
    ln_body(q + row * DIM, w, b, QN + row * DIM, threadIdx.x);
  else
    ln_body(p + (row - NQ) * DIM, w, b, PN + (row - NQ) * DIM, threadIdx.x);
}

// ---------------- merged transpose+cast: all 5 weights in one launch ------------
__global__ __launch_bounds__(256) void tcast_all_k(
    const float* __restrict__ wq, const float* __restrict__ wk,
    const float* __restrict__ wv, const float* __restrict__ w1,
    const float* __restrict__ w2, f16* WQT, f16* WKT, f16* WVT, f16* W1T,
    f16* W2T) {
  const int id = blockIdx.x;
  const float* X;
  f16* O;
  int R, C, tx, ty;
  if (id < 3072) {
    const int which = id >> 10, l = id & 1023;
    X = which == 0 ? wq : which == 1 ? wk : wv;
    O = which == 0 ? WQT : which == 1 ? WKT : WVT;
    R = 1024; C = 1024; tx = l & 31; ty = l >> 5;
  } else if (id < 7168) {
    const int l = id - 3072;
    X = w1; O = W1T; R = 1024; C = 4096; tx = l & 127; ty = l >> 7;
  } else {
    const int l = id - 7168;
    X = w2; O = W2T; R = 4096; C = 1024; tx = l & 31; ty = l >> 5;
  }
  __shared__ float tile[32][33];
  const int c0 = tx * 32, r0 = ty * 32;
  const int x = threadIdx.x, y = threadIdx.y;
#pragma unroll
  for (int j = 0; j < 4; ++j)
    tile[y + j * 8][x] = X[(long)(r0 + y + j * 8) * C + c0 + x];
  __syncthreads();
#pragma unroll
  for (int j = 0; j < 4; ++j)
    O[(long)(c0 + y + j * 8) * R + r0 + x] = (f16)tile[x][y + j * 8];
}

// ---------------- M_h partials from combined KV[1024][2048] ----------------
__global__ __launch_bounds__(256) void calc_m_part_k(const f16* __restrict__ KV,
                                                     float* __restrict__ Mp) {
  const int h = blockIdx.x, ch = blockIdx.y;
  const int t = threadIdx.x;
  const int d1 = t >> 2;
  const int d2b = (t & 3) * 16;
  float acc[16] = {};
  const int n0 = ch * (NW / MCHUNK);
#pragma unroll 4
  for (int n = n0; n < n0 + NW / MCHUNK; ++n) {
    const float kv = (float)KV[(long)n * 2048 + h * DHEAD + d1];
    const f16x8* vp = (const f16x8*)&KV[(long)n * 2048 + 1024 + h * DHEAD + d2b];
    const f16x8 v0 = vp[0], v1 = vp[1];
#pragma unroll
    for (int j = 0; j < 8; ++j) acc[j] += kv * (float)v0[j];
#pragma unroll
    for (int j = 0; j < 8; ++j) acc[8 + j] += kv * (float)v1[j];
  }
  float* o = &Mp[((long)(h * MCHUNK + ch)) * 4096 + d1 * 64 + d2b];
#pragma unroll
  for (int j = 0; j < 16; ++j) o[j] = acc[j];
}

__global__ __launch_bounds__(256) void calc_m_reduce_k(const float* __restrict__ Mp,
                                                       float* __restrict__ Mo) {
  const int h = blockIdx.x;
  const int t = threadIdx.x;
#pragma unroll
  for (int e = t; e < 4096; e += 256) {
    float s = 0.f;
#pragma unroll
    for (int c = 0; c < MCHUNK; ++c)
      s += Mp[((long)(h * MCHUNK + c)) * 4096 + e];
    Mo[h * 4096 + e] = s;
  }
}

// ---------------- W_eff^T[j][i] = sum_d M[h(i)][i%64][d] * wo[h*64+d][j] ----------------
__global__ __launch_bounds__(256) void calc_wefft_k(const float* __restrict__ M,
                                                    const float* __restrict__ wo,
                                                    f16* __restrict__ Wt) {
  const int h = blockIdx.x, jt = blockIdx.y;
  const int t = threadIdx.x;
  const int jl = t & 63;
  const int il0 = (t >> 6) * 16;
  const int j = jt * 64 + jl;
  float acc[16] = {};
  for (int d = 0; d < DHEAD; ++d) {
    const float w = wo[(long)(h * DHEAD + d) * DIM + j];
    const float* mrow = &M[h * 4096 + il0 * 64 + d];
#pragma unroll
    for (int r = 0; r < 16; ++r) acc[r] += mrow[r * 64] * w;
  }
#pragma unroll
  for (int r = 0; r < 16; ++r)
    Wt[(long)j * DIM + h * DHEAD + il0 + r] = (f16)acc[r];
}

// ======================= 256x256 one-barrier-per-tile GEMM (best platform) ======
// R14 config (583us, best measured). BK=64, 2 LDS bufs (128KB), straight-line
// tile body, single __syncthreads() per K-tile, launch_bounds(512,2), 116 VGPR.
// PLATEAU RECORD: 7 schedule/occupancy variants (2-phase, 3-buf lockstep,
// 8-phase counted-vmcnt, one-barrier, parity bursts, BK 32/64, 256/512-thr,
// 1-2 blk/CU) all land at 25-30% MfmaUtil (~700-830 TF) for these shapes.
// HARD CONSTRAINTS: acc[8][4]=128 AGPR => >2 waves/SIMD spills (R9/R10/R13:
// GBs of scratch WRITE_SIZE); 128^2 tile (64-AGPR acc) measured slower (R3).
enum {
  EPI_F16 = 0,       // f16 out
  EPI_L2N = 1,       // per-head l2norm, f16 out
  EPI_BIAS_RES = 2,  // f32 out = acc + bias + f32 resid (out may alias resid)
  EPI_GELU = 3,      // f16 out = gelu(acc + bias), sigmoid form
  EPI_KV = 4         // N=2048 combined K|V: c0<1024 -> l2norm (K half), else cast
};

template <int EPI>
__global__ __launch_bounds__(512, 2) void gemm256(
    const f16* __restrict__ A, const f16* __restrict__ Bt, int M, int N, int K,
    const float* __restrict__ bias, const float* resid, void* out) {
  __shared__ __align__(16) f16 lds[65536];  // 128KB: 2 bufs x {A[2][256][32], B[2][256][32]}

  const int tid = threadIdx.x;
  const int lane = tid & 63;
  const int wid = tid >> 6;   // 0..7
  const int wm = wid >> 2;    // 0..1
  const int wn = wid & 3;     // 0..3
  const int l15 = lane & 15;

  // M-slab XCD mapping (block orig -> XCD orig%8)
  int bm, bn;
  {
    const int orig = blockIdx.y * gridDim.x + blockIdx.x;
    if ((gridDim.x & 7) == 0) {
      const int slab = orig & 7;
      const int idx = orig >> 3;
      const int sm = gridDim.x >> 3;
      bm = slab * sm + idx % sm;
      bn = idx / sm;
    } else {
      bm = blockIdx.x;
      bn = blockIdx.y;
    }
  }

  const int scol8 = (((tid & 3) ^ ((tid >> 3) & 3))) * 8;
  const f16* aSrc = A + (long)(bm * 256 + (tid >> 2)) * K + scol8;
  const f16* bSrc = Bt + (long)(bn * 256 + (tid >> 2)) * K + scol8;
  const long hK = (long)128 * K;
  const int tid8 = tid * 8;

  const int rslot8 = (((lane >> 4) ^ ((l15 >> 1) & 3))) * 8;
  const int aRdBase = (wm * 128 + l15) * 32 + rslot8;
  const int bRdBase = 16384 + (wn * 64 + l15) * 32 + rslot8;

  f32x4 acc[8][4] = {};
  const int NT = K >> 6;

#define STAGE_A0(Ld, ko)                              \
  glds16(aSrc + (ko), (Ld) + tid8);                   \
  glds16(aSrc + hK + (ko), (Ld) + 4096 + tid8)
#define STAGE_A1(Ld, ko)                              \
  glds16(aSrc + (ko) + 32, (Ld) + 8192 + tid8);       \
  glds16(aSrc + hK + (ko) + 32, (Ld) + 8192 + 4096 + tid8)
#define STAGE_B0(Ld, ko)                              \
  glds16(bSrc + (ko), (Ld) + 16384 + tid8);           \
  glds16(bSrc + hK + (ko), (Ld) + 16384 + 4096 + tid8)
#define STAGE_B1(Ld, ko)                              \
  glds16(bSrc + (ko) + 32, (Ld) + 24576 + tid8);      \
  glds16(bSrc + hK + (ko) + 32, (Ld) + 24576 + 4096 + tid8)

#define BURST(AF, BF, MB)                                                 \
  __builtin_amdgcn_s_setprio(1);                                          \
  _Pragma("unroll") for (int j = 0; j < 4; ++j)                           \
      _Pragma("unroll") for (int nj = 0; nj < 4; ++nj)                    \
          acc[(MB) + j][nj] = __builtin_amdgcn_mfma_f32_16x16x32_f16(     \
              AF[j], BF[nj], acc[(MB) + j][nj], 0, 0, 0);                 \
  __builtin_amdgcn_s_setprio(0)

  // prologue
  STAGE_A0(lds, 0);
  STAGE_B0(lds, 0);
  STAGE_A1(lds, 0);
  STAGE_B1(lds, 0);
  __syncthreads();

  f16x8 bA[4], bB[4], aA[4], aB[4], aC[4], aD[4];
#pragma unroll
  for (int j = 0; j < 4; ++j) bA[j] = *(const f16x8*)&lds[bRdBase + j * 512];
#pragma unroll
  for (int j = 0; j < 4; ++j) aA[j] = *(const f16x8*)&lds[aRdBase + j * 512];

  for (int g = 0; g < NT; ++g) {
    f16* L = &lds[(g & 1) * 32768];
    f16* Lo = &lds[((g & 1) ^ 1) * 32768];
    const long ko1 = (long)(g + 1) * 64;
    const bool s1 = (g + 1) < NT;

    if (s1) { STAGE_A0(Lo, ko1); STAGE_B0(Lo, ko1); }
#pragma unroll
    for (int j = 0; j < 4; ++j)
      aB[j] = *(const f16x8*)&L[aRdBase + 2048 + j * 512];
    BURST(aA, bA, 0);          // ks0, mh0
    if (s1) { STAGE_A1(Lo, ko1); STAGE_B1(Lo, ko1); }
#pragma unroll
    for (int j = 0; j < 4; ++j)
      bB[j] = *(const f16x8*)&L[8192 + bRdBase + j * 512];
#pragma unroll
    for (int j = 0; j < 4; ++j)
      aC[j] = *(const f16x8*)&L[8192 + aRdBase + j * 512];
    BURST(aB, bA, 4);          // ks0, mh1
#pragma unroll
    for (int j = 0; j < 4; ++j)
      aD[j] = *(const f16x8*)&L[8192 + aRdBase + 2048 + j * 512];
    BURST(aC, bB, 0);          // ks1, mh0
    BURST(aD, bB, 4);          // ks1, mh1

    __syncthreads();
    if (s1) {
#pragma unroll
      for (int j = 0; j < 4; ++j) bA[j] = *(const f16x8*)&Lo[bRdBase + j * 512];
#pragma unroll
      for (int j = 0; j < 4; ++j) aA[j] = *(const f16x8*)&Lo[aRdBase + j * 512];
    }
  }
#undef STAGE_A0
#undef STAGE_A1
#undef STAGE_B0
#undef STAGE_B1
#undef BURST

  // epilogue
  const int r0 = bm * 256 + wm * 128;
  const int c0 = bn * 256 + wn * 64;
  const int lr = (lane >> 4) * 4;
  const int lc = l15;

#pragma unroll
  for (int mi = 0; mi < 8; ++mi) {
#pragma unroll
    for (int i = 0; i < 4; ++i) {
      const long r = r0 + mi * 16 + lr + i;
      if (EPI == EPI_L2N || EPI == EPI_KV) {
        if (EPI == EPI_L2N || c0 < 1024) {
          float ss = 0.f;
#pragma unroll
          for (int nj = 0; nj < 4; ++nj) {
            const float x = acc[mi][nj][i];
            ss += x * x;
          }
          ss += __shfl_xor(ss, 1);
          ss += __shfl_xor(ss, 2);
          ss += __shfl_xor(ss, 4);
          ss += __shfl_xor(ss, 8);
          const float inv = fast_rsq(fmaxf(ss, 1e-24f));
#pragma unroll
          for (int nj = 0; nj < 4; ++nj)
            ((f16*)out)[r * N + c0 + nj * 16 + lc] = (f16)(acc[mi][nj][i] * inv);
        } else {  // V half: plain cast
#pragma unroll
          for (int nj = 0; nj < 4; ++nj)
            ((f16*)out)[r * N + c0 + nj * 16 + lc] = (f16)acc[mi][nj][i];
        }
      } else if (EPI == EPI_F16) {
#pragma unroll
        for (int nj = 0; nj < 4; ++nj)
          ((f16*)out)[r * N + c0 + nj * 16 + lc] = (f16)acc[mi][nj][i];
      } else if (EPI == EPI_BIAS_RES) {
#pragma unroll
        for (int nj = 0; nj < 4; ++nj) {
          const long c2 = c0 + nj * 16 + lc;
          ((float*)out)[r * N + c2] = acc[mi][nj][i] + bias[c2] + resid[r * N + c2];
        }
      } else {  // EPI_GELU: x*sigmoid(1.5957691*(x+0.044715x^3)), exp+rcp only
#pragma unroll
        for (int nj = 0; nj < 4; ++nj) {
          const long c2 = c0 + nj * 16 + lc;
          const float x = acc[mi][nj][i] + bias[c2];
          const float x2 = x * x;
          const float t = __builtin_fmaf(0.044715f * x2, x, x);
          const float y = fminf(-1.5957691216057308f * t, 88.0f);
          const float z = __expf(y);
          ((f16*)out)[r * N + c2] = (f16)(x * fast_rcp(1.0f + z));
        }
      }
    }
  }
}

extern "C" void kernel_launch(void* const* d_in, const int* in_sizes, int n_in,
                              void* d_out, int out_size, void* d_ws, size_t ws_size,
                              hipStream_t stream) {
  (void)in_sizes; (void)n_in; (void)out_size;
  const float* queries = (const float*)d_in[0];
  const float* prototypes = (const float*)d_in[1];
  const float* ln1_w = (const float*)d_in[2];
  const float* ln1_b = (const float*)d_in[3];
  const float* wq = (const float*)d_in[4];
  const float* wk = (const float*)d_in[5];
  const float* wv = (const float*)d_in[6];
  const float* wo = (const float*)d_in[7];
  const float* bo = (const float*)d_in[8];
  const float* ln2_w = (const float*)d_in[9];
  const float* ln2_b = (const float*)d_in[10];
  const float* w1 = (const float*)d_in[11];
  const float* b1 = (const float*)d_in[12];
  const float* w2 = (const float*)d_in[13];
  const float* b2 = (const float*)d_in[14];

  char* ws = (char*)d_ws;
  const size_t MB = 1024ull * 1024ull;
  if (ws_size < 176ull * MB) return;  // layout needs 176MB

  // transient region (dead before MLP; G aliases it)
  f16* QN = (f16*)(ws + 0);             // 32MB [16384][1024]
  f16* QHAT = (f16*)(ws + 32 * MB);     // 32MB
  f16* PN = (f16*)(ws + 64 * MB);       // 2MB
  f16* WQT = (f16*)(ws + 66 * MB);      // 2MB
  f16* WKT = (f16*)(ws + 68 * MB);      // 2MB  (WKT|WVT contiguous = KV weights)
  f16* WVT = (f16*)(ws + 70 * MB);      // 2MB
  f16* KV = (f16*)(ws + 72 * MB);       // 4MB [1024][2048]: khat | v
  float* Mbuf = (float*)(ws + 76 * MB); // 256KB
  f16* WEFFT = (f16*)(ws + 77 * MB);    // 2MB
  float* Mpart = (float*)(ws + 0);      // 8MB, aliases QN (dead by then)
  // persistent region
  f16* G = (f16*)(ws + 0);              // 128MB [16384][4096], aliases transients
  f16* HBF = (f16*)(ws + 128 * MB);     // 32MB
  f16* W1T = (f16*)(ws + 160 * MB);     // 8MB [4096][1024]
  f16* W2T = (f16*)(ws + 168 * MB);     // 8MB [1024][4096]
  float* RES2 = (float*)d_out;          // residual2 lives in d_out (f32, 64MB)

  // LN1 (queries + prototypes, one launch)
  ln1_all_k<<<NQ + NW, 256, 0, stream>>>(queries, prototypes, ln1_w, ln1_b, QN, PN);
  // all 5 weight transpose-casts, one launch
  tcast_all_k<<<11264, dim3(32, 8), 0, stream>>>(wq, wk, wv, w1, w2, WQT, WKT,
                                                 WVT, W1T, W2T);

  // q projection (+fused per-head l2norm)
  gemm256<EPI_L2N><<<dim3(NQ / 256, DIM / 256), 512, 0, stream>>>(
      QN, WQT, NQ, DIM, DIM, nullptr, nullptr, QHAT);
  // merged k+v projection: N=2048 against WKT|WVT, l2norm on K half
  gemm256<EPI_KV><<<dim3(NW / 256, 2048 / 256), 512, 0, stream>>>(
      PN, WKT, NW, 2048, DIM, nullptr, nullptr, KV);

  // attention collapse
  calc_m_part_k<<<dim3(HEADS, MCHUNK), 256, 0, stream>>>(KV, Mpart);
  calc_m_reduce_k<<<HEADS, 256, 0, stream>>>(Mpart, Mbuf);
  calc_wefft_k<<<dim3(HEADS, 16), 256, 0, stream>>>(Mbuf, wo, WEFFT);

  // attn-out + wo + bias + residual -> RES2 (f32, in d_out)
  gemm256<EPI_BIAS_RES><<<dim3(NQ / 256, DIM / 256), 512, 0, stream>>>(
      QHAT, WEFFT, NQ, DIM, DIM, bo, queries, RES2);

  // LN2 (reads d_out f32)
  ln_f16_k<<<NQ, 256, 0, stream>>>(RES2, ln2_w, ln2_b, HBF);

  // MLP, unchunked, full grids
  gemm256<EPI_GELU><<<dim3(NQ / 256, MLPD / 256), 512, 0, stream>>>(
      HBF, W1T, NQ, MLPD, DIM, b1, nullptr, G);
  gemm256<EPI_BIAS_RES><<<dim3(NQ / 256, DIM / 256), 512, 0, stream>>>(
      G, W2T, NQ, DIM, MLPD, b2, RES2, (float*)d_out);
}

// Round 17
// 575.051 us; speedup vs baseline: 1.0423x; 1.0124x over previous
//
#include <hip/hip_runtime.h>
#include <hip/hip_bf16.h>

typedef _Float16 f16;
typedef __attribute__((ext_vector_type(8))) _Float16 f16x8;
typedef __attribute__((ext_vector_type(4))) _Float16 f16x4;
typedef __attribute__((ext_vector_type(4))) float f32x4;

#define DIM 1024
#define HEADS 16
#define DHEAD 64
#define MLPD 4096
#define NQ 16384
#define NW 1024
#define MCHUNK 32

#define WAITV(n) asm volatile("s_waitcnt vmcnt(" #n ")" ::: "memory")

// ---------------- async global->LDS (16B per lane) ----------------
__device__ __forceinline__ void glds16(const f16* g, f16* l) {
  __builtin_amdgcn_global_load_lds(
      (const __attribute__((address_space(1))) void*)g,
      (__attribute__((address_space(3))) void*)l, 16, 0, 0);
}

// fast 1/x and 1/sqrt(x) (v_rcp/v_rsq, ~1ulp; error budget 0.29 >> this)
__device__ __forceinline__ float fast_rcp(float x) {
  float r;
  asm("v_rcp_f32 %0, %1" : "=v"(r) : "v"(x));
  return r;
}
__device__ __forceinline__ float fast_rsq(float x) {
  float r;
  asm("v_rsq_f32 %0, %1" : "=v"(r) : "v"(x));
  return r;
}

// ---------------- LayerNorm(1024): f32 in -> f16 out ----------------
__device__ __forceinline__ void ln_body(const float* __restrict__ X,
                                        const float* __restrict__ w,
                                        const float* __restrict__ b,
                                        f16* __restrict__ O, int t) {
  const float4 v = ((const float4*)X)[t];
  float s = v.x + v.y + v.z + v.w;
  float s2 = v.x * v.x + v.y * v.y + v.z * v.z + v.w * v.w;
#pragma unroll
  for (int m = 1; m < 64; m <<= 1) {
    s += __shfl_xor(s, m);
    s2 += __shfl_xor(s2, m);
  }
  __shared__ float ps[4], ps2[4];
  const int lane = t & 63, wid = t >> 6;
  if (lane == 0) { ps[wid] = s; ps2[wid] = s2; }
  __syncthreads();
  s = ps[0] + ps[1] + ps[2] + ps[3];
  s2 = ps2[0] + ps2[1] + ps2[2] + ps2[3];
  const float mu = s * (1.0f / DIM);
  const float inv = rsqrtf(s2 * (1.0f / DIM) - mu * mu + 1e-5f);
  const float4 wv = ((const float4*)w)[t];
  const float4 bv = ((const float4*)b)[t];
  f16x4 o;
  o[0] = (f16)((v.x - mu) * inv * wv.x + bv.x);
  o[1] = (f16)((v.y - mu) * inv * wv.y + bv.y);
  o[2] = (f16)((v.z - mu) * inv * wv.z + bv.z);
  o[3] = (f16)((v.w - mu) * inv * wv.w + bv.w);
  *(f16x4*)(O + t * 4) = o;
}

__global__ __launch_bounds__(256) void ln_f16_k(
    const float* __restrict__ X, const float* __restrict__ w,
    const float* __restrict__ b, f16* __restrict__ O) {
  const long row = blockIdx.x;
  ln_body(X + row * DIM, w, b, O + row * DIM, threadIdx.x);
}

// merged LN1 for queries + prototypes (one launch)
__global__ __launch_bounds__(256) void ln1_all_k(
    const float* __restrict__ q, const float* __restrict__ p,
    const float* __restrict__ w, const float* __restrict__ b,
    f16* __restrict__ QN, f16* __restrict__ PN) {
  const long row = blockIdx.x;
  if (row < NQ)
    ln_body(q + row * DIM, w, b, QN + row * DIM, threadIdx.x);
  else
    ln_body(p + (row - NQ) * DIM, w, b, PN + (row - NQ) * DIM, threadIdx.x);
}

// ---------------- merged transpose+cast: all 5 weights in one launch ------------
__global__ __launch_bounds__(256) void tcast_all_k(
    const float* __restrict__ wq, const float* __restrict__ wk,
    const float* __restrict__ wv, const float* __restrict__ w1,
    const float* __restrict__ w2, f16* WQT, f16* WKT, f16* WVT, f16* W1T,
    f16* W2T) {
  const int id = blockIdx.x;
  const float* X;
  f16* O;
  int R, C, tx, ty;
  if (id < 3072) {
    const int which = id >> 10, l = id & 1023;
    X = which == 0 ? wq : which == 1 ? wk : wv;
    O = which == 0 ? WQT : which == 1 ? WKT : WVT;
    R = 1024; C = 1024; tx = l & 31; ty = l >> 5;
  } else if (id < 7168) {
    const int l = id - 3072;
    X = w1; O = W1T; R = 1024; C = 4096; tx = l & 127; ty = l >> 7;
  } else {
    const int l = id - 7168;
    X = w2; O = W2T; R = 4096; C = 1024; tx = l & 31; ty = l >> 5;
  }
  __shared__ float tile[32][33];
  const int c0 = tx * 32, r0 = ty * 32;
  const int x = threadIdx.x, y = threadIdx.y;
#pragma unroll
  for (int j = 0; j < 4; ++j)
    tile[y + j * 8][x] = X[(long)(r0 + y + j * 8) * C + c0 + x];
  __syncthreads();
#pragma unroll
  for (int j = 0; j < 4; ++j)
    O[(long)(c0 + y + j * 8) * R + r0 + x] = (f16)tile[x][y + j * 8];
}

// ---------------- M_h partials from combined KV[1024][2048] ----------------
__global__ __launch_bounds__(256) void calc_m_part_k(const f16* __restrict__ KV,
                                                     float* __restrict__ Mp) {
  const int h = blockIdx.x, ch = blockIdx.y;
  const int t = threadIdx.x;
  const int d1 = t >> 2;
  const int d2b = (t & 3) * 16;
  float acc[16] = {};
  const int n0 = ch * (NW / MCHUNK);
#pragma unroll 4
  for (int n = n0; n < n0 + NW / MCHUNK; ++n) {
    const float kv = (float)KV[(long)n * 2048 + h * DHEAD + d1];
    const f16x8* vp = (const f16x8*)&KV[(long)n * 2048 + 1024 + h * DHEAD + d2b];
    const f16x8 v0 = vp[0], v1 = vp[1];
#pragma unroll
    for (int j = 0; j < 8; ++j) acc[j] += kv * (float)v0[j];
#pragma unroll
    for (int j = 0; j < 8; ++j) acc[8 + j] += kv * (float)v1[j];
  }
  float* o = &Mp[((long)(h * MCHUNK + ch)) * 4096 + d1 * 64 + d2b];
#pragma unroll
  for (int j = 0; j < 16; ++j) o[j] = acc[j];
}

__global__ __launch_bounds__(256) void calc_m_reduce_k(const float* __restrict__ Mp,
                                                       float* __restrict__ Mo) {
  const int h = blockIdx.x;
  const int t = threadIdx.x;
#pragma unroll
  for (int e = t; e < 4096; e += 256) {
    float s = 0.f;
#pragma unroll
    for (int c = 0; c < MCHUNK; ++c)
      s += Mp[((long)(h * MCHUNK + c)) * 4096 + e];
    Mo[h * 4096 + e] = s;
  }
}

// ---------------- W_eff^T[j][i] = sum_d M[h(i)][i%64][d] * wo[h*64+d][j] ----------------
__global__ __launch_bounds__(256) void calc_wefft_k(const float* __restrict__ M,
                                                    const float* __restrict__ wo,
                                                    f16* __restrict__ Wt) {
  const int h = blockIdx.x, jt = blockIdx.y;
  const int t = threadIdx.x;
  const int jl = t & 63;
  const int il0 = (t >> 6) * 16;
  const int j = jt * 64 + jl;
  float acc[16] = {};
  for (int d = 0; d < DHEAD; ++d) {
    const float w = wo[(long)(h * DHEAD + d) * DIM + j];
    const float* mrow = &M[h * 4096 + il0 * 64 + d];
#pragma unroll
    for (int r = 0; r < 16; ++r) acc[r] += mrow[r * 64] * w;
  }
#pragma unroll
  for (int r = 0; r < 16; ++r)
    Wt[(long)j * DIM + h * DHEAD + il0 + r] = (f16)acc[r];
}

// ============ 256x256 GEMM: BK=32, 3-buf, counted-vmcnt, unroll-by-3 ============
// Depth-2 prefetch without the R9/R10 spill: STATIC buffer binding via 3x
// unrolled steady loop (no runtime %3, no branch-duplicated bodies), single
// burst order. Protocol per sub-step: STAGE(tile t+2) -> 12 ds_read + 32 MFMA
// -> WAITV(4) [t+1 landed, t+2 in flight] -> s_barrier. vmcnt never drains to
// 0 in steady state. Requires NT % 3 == 2 (K=1024 -> NT=32, K=4096 -> NT=128).
// LDS 96KB = 3 x {A[256][32], B[256][32]}. launch_bounds(512,2): 128-AGPR acc
// forbids >2 waves/SIMD (R9/R10/R13: spill => GBs of scratch WRITE_SIZE).
enum {
  EPI_F16 = 0,       // f16 out
  EPI_L2N = 1,       // per-head l2norm, f16 out
  EPI_BIAS_RES = 2,  // f32 out = acc + bias + f32 resid (out may alias resid)
  EPI_GELU = 3,      // f16 out = gelu(acc + bias), sigmoid form
  EPI_KV = 4         // N=2048 combined K|V: c0<1024 -> l2norm (K half), else cast
};

template <int EPI>
__global__ __launch_bounds__(512, 2) void gemm256(
    const f16* __restrict__ A, const f16* __restrict__ Bt, int M, int N, int K,
    const float* __restrict__ bias, const float* resid, void* out) {
  __shared__ __align__(16) f16 lds[49152];  // 96KB: 3 bufs x 32KB

  const int tid = threadIdx.x;
  const int lane = tid & 63;
  const int wid = tid >> 6;   // 0..7
  const int wm = wid >> 2;    // 0..1
  const int wn = wid & 3;     // 0..3
  const int l15 = lane & 15;

  // M-slab XCD mapping (block orig -> XCD orig%8)
  int bm, bn;
  {
    const int orig = blockIdx.y * gridDim.x + blockIdx.x;
    if ((gridDim.x & 7) == 0) {
      const int slab = orig & 7;
      const int idx = orig >> 3;
      const int sm = gridDim.x >> 3;
      bm = slab * sm + idx % sm;
      bn = idx / sm;
    } else {
      bm = blockIdx.x;
      bn = blockIdx.y;
    }
  }

  // staging: thread t -> rows (t>>2), 128+(t>>2); slot t&3; source col pre-XORed
  // with ((t>>3)&3) = ((row>>1)&3) (both-sides involution with the ds_read XOR)
  const int scol8 = (((tid & 3) ^ ((tid >> 3) & 3))) * 8;
  const f16* aSrc = A + (long)(bm * 256 + (tid >> 2)) * K + scol8;
  const f16* bSrc = Bt + (long)(bn * 256 + (tid >> 2)) * K + scol8;
  const long hK = (long)128 * K;
  const int tid8 = tid * 8;

  const int rslot8 = (((lane >> 4) ^ ((l15 >> 1) & 3))) * 8;
  const int aRdBase = (wm * 128 + l15) * 32 + rslot8;
  const int bRdBase = 8192 + (wn * 64 + l15) * 32 + rslot8;

  f32x4 acc[8][4] = {};
  const int NT = K >> 5;  // BK=32 tiles; all launches here have NT % 3 == 2

  f16* const U0 = &lds[0];
  f16* const U1 = &lds[16384];
  f16* const U2 = &lds[32768];

#define STAGE(Ld, t)                                   \
  {                                                    \
    const long ko = (long)(t) * 32;                    \
    glds16(aSrc + ko, (Ld) + tid8);                    \
    glds16(aSrc + hK + ko, (Ld) + 4096 + tid8);        \
    glds16(bSrc + ko, (Ld) + 8192 + tid8);             \
    glds16(bSrc + hK + ko, (Ld) + 12288 + tid8);       \
  }

#define BURST(AF, BF, MB)                                                 \
  __builtin_amdgcn_s_setprio(1);                                          \
  _Pragma("unroll") for (int j = 0; j < 4; ++j)                           \
      _Pragma("unroll") for (int nj = 0; nj < 4; ++nj)                    \
          acc[(MB) + j][nj] = __builtin_amdgcn_mfma_f32_16x16x32_f16(     \
              AF[j], BF[nj], acc[(MB) + j][nj], 0, 0, 0);                 \
  __builtin_amdgcn_s_setprio(0)

#define TILE_BODY(L)                                                      \
  {                                                                       \
    f16x8 aA[4], aB[4], bA[4];                                            \
    _Pragma("unroll") for (int j = 0; j < 4; ++j)                         \
        bA[j] = *(const f16x8*)&(L)[bRdBase + j * 512];                   \
    _Pragma("unroll") for (int j = 0; j < 4; ++j)                         \
        aA[j] = *(const f16x8*)&(L)[aRdBase + j * 512];                   \
    _Pragma("unroll") for (int j = 0; j < 4; ++j)                         \
        aB[j] = *(const f16x8*)&(L)[aRdBase + 2048 + j * 512];            \
    BURST(aA, bA, 0);                                                     \
    BURST(aB, bA, 4);                                                     \
  }

#define BOUND4 WAITV(4); __builtin_amdgcn_s_barrier(); __builtin_amdgcn_sched_barrier(0)

  // prologue: stage tiles 0,1; wait tile 0 only (tile 1 stays in flight)
  STAGE(U0, 0);
  STAGE(U1, 1);
  WAITV(4);
  __builtin_amdgcn_s_barrier();
  __builtin_amdgcn_sched_barrier(0);

  // steady loop: m groups of 3 tiles, branch-free (stages tiles 2..NT-1)
  const int m3 = (NT - 2) / 3;
  for (int j = 0; j < m3; ++j) {
    const long t0 = 3L * j;
    STAGE(U2, t0 + 2);   // buf2 free: its last readers passed prev group's barrier
    TILE_BODY(U0);       // tile 3j   (landed)
    BOUND4;              // ensures tile 3j+1 landed; 3j+2 stays in flight
    STAGE(U0, t0 + 3);
    TILE_BODY(U1);       // tile 3j+1
    BOUND4;              // tile 3j+2 landed
    STAGE(U1, t0 + 4);
    TILE_BODY(U2);       // tile 3j+2
    BOUND4;              // tile 3j+3 landed
  }
  // tail: tiles NT-2 (buf0), NT-1 (buf1)
  TILE_BODY(U0);
  WAITV(0);
  __builtin_amdgcn_s_barrier();
  __builtin_amdgcn_sched_barrier(0);
  TILE_BODY(U1);

#undef STAGE
#undef BURST
#undef TILE_BODY
#undef BOUND4

  // epilogue
  const int r0 = bm * 256 + wm * 128;
  const int c0 = bn * 256 + wn * 64;
  const int lr = (lane >> 4) * 4;
  const int lc = l15;

#pragma unroll
  for (int mi = 0; mi < 8; ++mi) {
#pragma unroll
    for (int i = 0; i < 4; ++i) {
      const long r = r0 + mi * 16 + lr + i;
      if (EPI == EPI_L2N || EPI == EPI_KV) {
        if (EPI == EPI_L2N || c0 < 1024) {
          float ss = 0.f;
#pragma unroll
          for (int nj = 0; nj < 4; ++nj) {
            const float x = acc[mi][nj][i];
            ss += x * x;
          }
          ss += __shfl_xor(ss, 1);
          ss += __shfl_xor(ss, 2);
          ss += __shfl_xor(ss, 4);
          ss += __shfl_xor(ss, 8);
          const float inv = fast_rsq(fmaxf(ss, 1e-24f));
#pragma unroll
          for (int nj = 0; nj < 4; ++nj)
            ((f16*)out)[r * N + c0 + nj * 16 + lc] = (f16)(acc[mi][nj][i] * inv);
        } else {  // V half: plain cast
#pragma unroll
          for (int nj = 0; nj < 4; ++nj)
            ((f16*)out)[r * N + c0 + nj * 16 + lc] = (f16)acc[mi][nj][i];
        }
      } else if (EPI == EPI_F16) {
#pragma unroll
        for (int nj = 0; nj < 4; ++nj)
          ((f16*)out)[r * N + c0 + nj * 16 + lc] = (f16)acc[mi][nj][i];
      } else if (EPI == EPI_BIAS_RES) {
#pragma unroll
        for (int nj = 0; nj < 4; ++nj) {
          const long c2 = c0 + nj * 16 + lc;
          ((float*)out)[r * N + c2] = acc[mi][nj][i] + bias[c2] + resid[r * N + c2];
        }
      } else {  // EPI_GELU: x*sigmoid(1.5957691*(x+0.044715x^3)), exp+rcp only
#pragma unroll
        for (int nj = 0; nj < 4; ++nj) {
          const long c2 = c0 + nj * 16 + lc;
          const float x = acc[mi][nj][i] + bias[c2];
          const float x2 = x * x;
          const float t = __builtin_fmaf(0.044715f * x2, x, x);
          const float y = fminf(-1.5957691216057308f * t, 88.0f);
          const float z = __expf(y);
          ((f16*)out)[r * N + c2] = (f16)(x * fast_rcp(1.0f + z));
        }
      }
    }
  }
}

extern "C" void kernel_launch(void* const* d_in, const int* in_sizes, int n_in,
                              void* d_out, int out_size, void* d_ws, size_t ws_size,
                              hipStream_t stream) {
  (void)in_sizes; (void)n_in; (void)out_size;
  const float* queries = (const float*)d_in[0];
  const float* prototypes = (const float*)d_in[1];
  const float* ln1_w = (const float*)d_in[2];
  const float* ln1_b = (const float*)d_in[3];
  const float* wq = (const float*)d_in[4];
  const float* wk = (const float*)d_in[5];
  const float* wv = (const float*)d_in[6];
  const float* wo = (const float*)d_in[7];
  const float* bo = (const float*)d_in[8];
  const float* ln2_w = (const float*)d_in[9];
  const float* ln2_b = (const float*)d_in[10];
  const float* w1 = (const float*)d_in[11];
  const float* b1 = (const float*)d_in[12];
  const float* w2 = (const float*)d_in[13];
  const float* b2 = (const float*)d_in[14];

  char* ws = (char*)d_ws;
  const size_t MB = 1024ull * 1024ull;
  if (ws_size < 176ull * MB) return;  // layout needs 176MB

  // transient region (dead before MLP; G aliases it)
  f16* QN = (f16*)(ws + 0);             // 32MB [16384][1024]
  f16* QHAT = (f16*)(ws + 32 * MB);     // 32MB
  f16* PN = (f16*)(ws + 64 * MB);       // 2MB
  f16* WQT = (f16*)(ws + 66 * MB);      // 2MB
  f16* WKT = (f16*)(ws + 68 * MB);      // 2MB  (WKT|WVT contiguous = KV weights)
  f16* WVT = (f16*)(ws + 70 * MB);      // 2MB
  f16* KV = (f16*)(ws + 72 * MB);       // 4MB [1024][2048]: khat | v
  float* Mbuf = (float*)(ws + 76 * MB); // 256KB
  f16* WEFFT = (f16*)(ws + 77 * MB);    // 2MB
  float* Mpart = (float*)(ws + 0);      // 8MB, aliases QN (dead by then)
  // persistent region
  f16* G = (f16*)(ws + 0);              // 128MB [16384][4096], aliases transients
  f16* HBF = (f16*)(ws + 128 * MB);     // 32MB
  f16* W1T = (f16*)(ws + 160 * MB);     // 8MB [4096][1024]
  f16* W2T = (f16*)(ws + 168 * MB);     // 8MB [1024][4096]
  float* RES2 = (float*)d_out;          // residual2 lives in d_out (f32, 64MB)

  // LN1 (queries + prototypes, one launch)
  ln1_all_k<<<NQ + NW, 256, 0, stream>>>(queries, prototypes, ln1_w, ln1_b, QN, PN);
  // all 5 weight transpose-casts, one launch
  tcast_all_k<<<11264, dim3(32, 8), 0, stream>>>(wq, wk, wv, w1, w2, WQT, WKT,
                                                 WVT, W1T, W2T);

  // q projection (+fused per-head l2norm)
  gemm256<EPI_L2N><<<dim3(NQ / 256, DIM / 256), 512, 0, stream>>>(
      QN, WQT, NQ, DIM, DIM, nullptr, nullptr, QHAT);
  // merged k+v projection: N=2048 against WKT|WVT, l2norm on K half
  gemm256<EPI_KV><<<dim3(NW / 256, 2048 / 256), 512, 0, stream>>>(
      PN, WKT, NW, 2048, DIM, nullptr, nullptr, KV);

  // attention collapse
  calc_m_part_k<<<dim3(HEADS, MCHUNK), 256, 0, stream>>>(KV, Mpart);
  calc_m_reduce_k<<<HEADS, 256, 0, stream>>>(Mpart, Mbuf);
  calc_wefft_k<<<dim3(HEADS, 16), 256, 0, stream>>>(Mbuf, wo, WEFFT);

  // attn-out + wo + bias + residual -> RES2 (f32, in d_out)
  gemm256<EPI_BIAS_RES><<<dim3(NQ / 256, DIM / 256), 512, 0, stream>>>(
      QHAT, WEFFT, NQ, DIM, DIM, bo, queries, RES2);

  // LN2 (reads d_out f32)
  ln_f16_k<<<NQ, 256, 0, stream>>>(RES2, ln2_w, ln2_b, HBF);

  // MLP, unchunked, full grids
  gemm256<EPI_GELU><<<dim3(NQ / 256, MLPD / 256), 512, 0, stream>>>(
      HBF, W1T, NQ, MLPD, DIM, b1, nullptr, G);
  gemm256<EPI_BIAS_RES><<<dim3(NQ / 256, DIM / 256), 512, 0, stream>>>(
      G, W2T, NQ, DIM, MLPD, b2, RES2, (float*)d_out);
}